// Round 3
// baseline (683.922 us; speedup 1.0000x reference)
//
#include <hip/hip_runtime.h>
#include <math.h>

#define BB 64
#define SS 4096
#define DD 512

// t[b,d] = sum_k topic[b,k] * W[k,d]
__global__ __launch_bounds__(256) void tW_kernel(const float* __restrict__ topic,
                                                 const float* __restrict__ W,
                                                 float* __restrict__ t) {
    __shared__ float tp[DD];
    __shared__ float4 part[256];
    const int b      = blockIdx.x >> 2;
    const int dchunk = (blockIdx.x & 3) * 32;   // float4 units
    const int dg     = threadIdx.x & 31;
    const int strip  = threadIdx.x >> 5;        // 0..7, each owns 64 k
    for (int i = threadIdx.x; i < DD; i += 256) tp[i] = topic[b * DD + i];
    __syncthreads();
    const float4* W4 = (const float4*)W;        // row stride 128 float4
    float4 acc = {0.f, 0.f, 0.f, 0.f};
    const int k0 = strip * 64;
#pragma unroll 8
    for (int k = 0; k < 64; ++k) {
        const float s  = tp[k0 + k];
        const float4 w = W4[(size_t)(k0 + k) * 128 + dchunk + dg];
        acc.x += s * w.x; acc.y += s * w.y; acc.z += s * w.z; acc.w += s * w.w;
    }
    part[threadIdx.x] = acc;
    __syncthreads();
    if (threadIdx.x < 32) {
        float4 r = part[threadIdx.x];
#pragma unroll
        for (int st = 1; st < 8; ++st) {
            const float4 q = part[st * 32 + threadIdx.x];
            r.x += q.x; r.y += q.y; r.z += q.z; r.w += q.w;
        }
        ((float4*)(t + b * DD))[dchunk + dg] = r;
    }
}

// scores[b,s] = t[b] . seq[b,s] + bias
// 4 lanes per score, 16 scores per wave, 64 scores per block.
// Only 2 shuffle steps per 16 scores; 4 independent loads in flight.
__global__ __launch_bounds__(256) void scores_kernel(const float* __restrict__ t,
                                                     const float* __restrict__ seq,
                                                     const float* __restrict__ bias,
                                                     float* __restrict__ scores) {
    __shared__ float4 tsh[128];
    const int b = blockIdx.y;
    if (threadIdx.x < 128) tsh[threadIdx.x] = ((const float4*)(t + b * DD))[threadIdx.x];
    __syncthreads();

    const int wave    = threadIdx.x >> 6;
    const int lane    = threadIdx.x & 63;
    const int d_part  = lane & 3;        // which quarter-of-64B within a row chunk
    const int s_local = lane >> 2;       // 0..15
    const int s       = (blockIdx.x * 4 + wave) * 16 + s_local;

    const float4* row = (const float4*)(seq + ((size_t)b * SS + s) * DD);

    float a0 = 0.f, a1 = 0.f, a2 = 0.f, a3 = 0.f;
    for (int j = 0; j < 32; j += 4) {
        const float4 v0 = row[(j + 0) * 4 + d_part];
        const float4 v1 = row[(j + 1) * 4 + d_part];
        const float4 v2 = row[(j + 2) * 4 + d_part];
        const float4 v3 = row[(j + 3) * 4 + d_part];
        const float4 t0 = tsh[(j + 0) * 4 + d_part];
        const float4 t1 = tsh[(j + 1) * 4 + d_part];
        const float4 t2 = tsh[(j + 2) * 4 + d_part];
        const float4 t3 = tsh[(j + 3) * 4 + d_part];
        a0 += v0.x * t0.x + v0.y * t0.y + v0.z * t0.z + v0.w * t0.w;
        a1 += v1.x * t1.x + v1.y * t1.y + v1.z * t1.z + v1.w * t1.w;
        a2 += v2.x * t2.x + v2.y * t2.y + v2.z * t2.z + v2.w * t2.w;
        a3 += v3.x * t3.x + v3.y * t3.y + v3.z * t3.z + v3.w * t3.w;
    }
    float partial = (a0 + a1) + (a2 + a3);
    partial += __shfl_xor(partial, 1, 64);
    partial += __shfl_xor(partial, 2, 64);
    if (d_part == 0) scores[(size_t)b * SS + s] = partial + bias[0];
}

// row softmax over S=4096, one block of 1024 threads per row (float4/thread)
__global__ __launch_bounds__(1024) void softmax_kernel(const float* __restrict__ scores,
                                                       float* __restrict__ out) {
    __shared__ float red[16];
    const int b   = blockIdx.x;
    const int tid = threadIdx.x;
    const int wave = tid >> 6, lane = tid & 63;

    const float4 v = ((const float4*)(scores + (size_t)b * SS))[tid];

    float m = fmaxf(fmaxf(v.x, v.y), fmaxf(v.z, v.w));
#pragma unroll
    for (int k = 32; k; k >>= 1) m = fmaxf(m, __shfl_xor(m, k, 64));
    if (lane == 0) red[wave] = m;
    __syncthreads();
    if (tid < 16) {
        float x = red[tid];
#pragma unroll
        for (int k = 8; k; k >>= 1) x = fmaxf(x, __shfl_xor(x, k, 16));
        if (tid == 0) red[0] = x;
    }
    __syncthreads();
    m = red[0];
    __syncthreads();

    float4 e;
    e.x = __expf(v.x - m); e.y = __expf(v.y - m);
    e.z = __expf(v.z - m); e.w = __expf(v.w - m);
    float s = e.x + e.y + e.z + e.w;
#pragma unroll
    for (int k = 32; k; k >>= 1) s += __shfl_xor(s, k, 64);
    if (lane == 0) red[wave] = s;
    __syncthreads();
    if (tid < 16) {
        float x = red[tid];
#pragma unroll
        for (int k = 8; k; k >>= 1) x += __shfl_xor(x, k, 16);
        if (tid == 0) red[0] = x;
    }
    __syncthreads();
    const float inv = 1.f / red[0];

    float4 o;
    o.x = e.x * inv; o.y = e.y * inv; o.z = e.z * inv; o.w = e.w * inv;
    ((float4*)(out + (size_t)b * SS))[tid] = o;
}

extern "C" void kernel_launch(void* const* d_in, const int* in_sizes, int n_in,
                              void* d_out, int out_size, void* d_ws, size_t ws_size,
                              hipStream_t stream) {
    const float* topic = (const float*)d_in[0];   // [B, D]
    const float* seq   = (const float*)d_in[1];   // [B, S, D]
    const float* W     = (const float*)d_in[2];   // [D, D]
    const float* bias  = (const float*)d_in[3];   // [1]
    float* out = (float*)d_out;                   // [B, S]

    float* t      = (float*)d_ws;                 // B*D floats
    float* scores = t + BB * DD;                  // B*S floats

    tW_kernel<<<dim3(BB * 4), 256, 0, stream>>>(topic, W, t);
    scores_kernel<<<dim3(SS / 64, BB), 256, 0, stream>>>(t, seq, bias, scores);
    softmax_kernel<<<dim3(BB), 1024, 0, stream>>>(scores, out);
}